// Round 15
// baseline (20.314 us; speedup 1.0000x reference)
//
#include <hip/hip_runtime.h>

// RankingBCELoss: loss = (1/(n_pos*n_neg)) * sum_{p,n} log(1 + e^{x_n} * e^{-x_p})
// R15: masked-linear staging (no scan, no scatter, no LDS conflicts), RB=64.
//  Post-mortems: R14 launch_bounds neutral (spill theory dead). R13's K1 costs:
//  512x redundant 128KB L2 re-reads + a ~16-32-way bank-conflicted compacted
//  scatter (idx ~ 16*tid -> 2 banks/wave). R11 books -> ~4us/node floor: keep 2 nodes.
//  K1 (256 blocks x 512 thr = 1 block/CU):
//    - wave 0 full-wave ballot-compacts its 64 raw rows' e^{-x_pos} -> lds_emp
//    - all threads: 8x float4/int4 coalesced loads (L2-resident), 32 masked
//      exps, 8x conflict-free ds_write_b128 linear stores; count negatives
//      (targets are {0,1} per reference -> np = n - nn; nn identical across blocks)
//    - ONE barrier; template<NQ=1..8> product-of-8 hot loop over all 16384
//      masked cols (masked term = fma(0,emp,1) = 1, absorbed free; 1 v_log_f32
//      per 8 rows per col)
//    - block reduce -> partials[bid], cnts[bid]. No atomics, no fences.
//  K2 (1 wave): sum 256 partials + cnts[0] -> out. No tg re-read.

#define PT   512           // K1 threads per block (8 waves)
#define RB   64            // raw rows per block (one full wave's ballot)
#define NB   256           // K1 blocks (n / RB)

template<int NQ>
__device__ __forceinline__ float row_stream(const float* __restrict__ lds_en,
                                            const float* __restrict__ lds_emp,
                                            int nf4, int tid) {
    float emp[NQ * 8];                       // template-static indices => registers
#pragma unroll
    for (int r = 0; r < NQ * 8; ++r) emp[r] = lds_emp[r];
    float acc[NQ];
#pragma unroll
    for (int q = 0; q < NQ; ++q) acc[q] = 0.f;

    auto do_col = [&](float en) {
        // en, emp in [0, ~90]; term = 1+en*emp in [1, ~8100];
        // product of 8 <= 8100^8 ~ 2e31 < 3.4e38: safe. Masked en=0 -> all terms 1.
#pragma unroll
        for (int q = 0; q < NQ; ++q) {
            float p0 = __builtin_fmaf(en, emp[q * 8 + 0], 1.f);
            p0 *= __builtin_fmaf(en, emp[q * 8 + 1], 1.f);
            p0 *= __builtin_fmaf(en, emp[q * 8 + 2], 1.f);
            p0 *= __builtin_fmaf(en, emp[q * 8 + 3], 1.f);
            float p1 = __builtin_fmaf(en, emp[q * 8 + 4], 1.f);
            p1 *= __builtin_fmaf(en, emp[q * 8 + 5], 1.f);
            p1 *= __builtin_fmaf(en, emp[q * 8 + 6], 1.f);
            p1 *= __builtin_fmaf(en, emp[q * 8 + 7], 1.f);
            acc[q] += __log2f(p0 * p1);
        }
    };

    const float4* __restrict__ en4 = (const float4*)lds_en;
#pragma unroll 2
    for (int v = tid; v < nf4; v += PT) {    // consecutive lanes -> consecutive 16B
        const float4 e4 = en4[v];
        do_col(e4.x);
        do_col(e4.y);
        do_col(e4.z);
        do_col(e4.w);
    }
    float s = 0.f;
#pragma unroll
    for (int q = 0; q < NQ; ++q) s += acc[q];
    return s;
}

__global__ __launch_bounds__(PT, 4)          // VGPR cap 128 (emp[64]+acc[8]+misc ~95)
void pair_local(const float* __restrict__ x, const int* __restrict__ tg, int n,
                double* __restrict__ partials, int* __restrict__ cnts) {
    __shared__ float  lds_en[16384];         // 64 KB masked exp(x_neg), linear
    __shared__ float  lds_emp[RB];
    __shared__ int    lds_k;
    __shared__ double wsum[PT / 64];
    __shared__ int    wcnt[PT / 64];
    const int bid = blockIdx.x, tid = threadIdx.x;
    const int lane = tid & 63, wid = tid >> 6;
    const int n4 = n >> 2;                   // 4096 (n = 16384)

    // ---- wave 0: full-wave ballot-compact this block's 64 raw rows ----
    if (wid == 0) {
        const int row = bid * RB + lane;     // lane 0..63 <-> row
        float ex = 0.f; int isp = 0;
        if (row < n) {
            isp = (tg[row] == 1);
            if (isp) ex = __expf(-x[row]);
        }
        const unsigned long long m = __ballot(isp);
        lds_emp[lane] = 0.f;                 // zero-fill; rank store below wins (same wave)
        const int rank = (int)__popcll(m & ((1ull << lane) - 1ull));
        if (isp) lds_emp[rank] = ex;
        if (lane == 0) lds_k = (int)__popcll(m);
    }

    // ---- all threads: masked-linear staging (no scan, no scatter) ----
    int cn = 0;
#pragma unroll
    for (int k = 0; k < 8; ++k) {
        const int v = tid + (k << 9);        // tid + k*512; < 4096 for n=16384
        float4 e = make_float4(0.f, 0.f, 0.f, 0.f);
        if (v < n4) {
            const float4 xq = ((const float4*)x)[v];
            const int4   tq = ((const int4*)tg)[v];
            e.x = (tq.x == 0) ? __expf(xq.x) : 0.f;
            e.y = (tq.y == 0) ? __expf(xq.y) : 0.f;
            e.z = (tq.z == 0) ? __expf(xq.z) : 0.f;
            e.w = (tq.w == 0) ? __expf(xq.w) : 0.f;
            cn += (tq.x == 0) + (tq.y == 0) + (tq.z == 0) + (tq.w == 0);
        }
        ((float4*)lds_en)[v] = e;            // conflict-free ds_write_b128
    }
    __syncthreads();                         // the ONLY barrier before reductions

    // ---- hot loop over all masked cols (uniform branch) ----
    const int kq = (lds_k + 7) >> 3;         // 0..8 row groups of 8
    float s = 0.f;
    switch (kq) {
        case 0: break;
        case 1: s = row_stream<1>(lds_en, lds_emp, n4, tid); break;
        case 2: s = row_stream<2>(lds_en, lds_emp, n4, tid); break;
        case 3: s = row_stream<3>(lds_en, lds_emp, n4, tid); break;
        case 4: s = row_stream<4>(lds_en, lds_emp, n4, tid); break;
        case 5: s = row_stream<5>(lds_en, lds_emp, n4, tid); break;
        case 6: s = row_stream<6>(lds_en, lds_emp, n4, tid); break;
        case 7: s = row_stream<7>(lds_en, lds_emp, n4, tid); break;
        default: s = row_stream<8>(lds_en, lds_emp, n4, tid); break;
    }

    // ---- block reduction -> partials[bid], cnts[bid]; no atomics/fences ----
#pragma unroll
    for (int off = 32; off > 0; off >>= 1) {
        s  += __shfl_down(s, off, 64);
        cn += __shfl_down(cn, off, 64);
    }
    if (lane == 0) { wsum[wid] = (double)s; wcnt[wid] = cn; }
    __syncthreads();
    if (tid == 0) {
        double b = 0.0; int t = 0;
#pragma unroll
        for (int w = 0; w < PT / 64; ++w) { b += wsum[w]; t += wcnt[w]; }
        partials[bid] = b;
        cnts[bid] = t;                       // global nn (identical for all blocks)
    }
}

// ---- K2: one wave sums 256 partials; np = n - nn (targets are {0,1}) ----
__global__ __launch_bounds__(64)
void finalize_kernel(const double* __restrict__ partials, const int* __restrict__ cnts,
                     int nb, int n, float* __restrict__ out) {
    const int lane = threadIdx.x;            // 0..63, one wave
    double d = 0.0;
    for (int k = lane; k < nb; k += 64) d += partials[k];   // fixed order
#pragma unroll
    for (int off = 32; off > 0; off >>= 1) d += __shfl_down(d, off, 64);
    if (lane == 0) {
        const int nn = cnts[0];
        const int np = n - nn;               // targets strictly {0,1}
        const double npairs = (double)np * (double)nn;
        out[0] = (npairs > 0.0) ? (float)(d * 0.6931471805599453 / npairs) : 0.0f;
    }
}

extern "C" void kernel_launch(void* const* d_in, const int* in_sizes, int n_in,
                              void* d_out, int out_size, void* d_ws, size_t ws_size,
                              hipStream_t stream) {
    const float* x  = (const float*)d_in[0];
    const int*   tg = (const int*)d_in[1];
    const int n = in_sizes[0];                 // 16384

    char* ws = (char*)d_ws;
    double* partials = (double*)(ws);          // NB doubles = 2 KB
    int*    cnts     = (int*)(ws + 4096);      // NB ints

    const int nblocks = (n + RB - 1) / RB;     // 256
    pair_local<<<nblocks, PT, 0, stream>>>(x, tg, n, partials, cnts);
    finalize_kernel<<<1, 64, 0, stream>>>(partials, cnts, nblocks, n, (float*)d_out);
}